// Round 1
// 400.795 us; speedup vs baseline: 1.0548x; 1.0548x over previous
//
#include <hip/hip_runtime.h>

#define BB 2
#define LL 384
#define DD 128
#define NH 8

typedef const float* fp32p;

// ---------------- K1: projections + point rotation ----------------
// grid 768 (b*L+l), block 128
__global__ __launch_bounds__(128) void k_proj(
    fp32p x, fp32p r, fp32p tvec,
    fp32p Wqs, fp32p Wks, fp32p Wvs,
    fp32p Wqp, fp32p Wkp, fp32p Wvp,
    float* qs, float* ks, float* vs,
    float* qp, float* kp, float* vp)
{
  int bl = blockIdx.x;
  int t = threadIdx.x;
  __shared__ float xs[128];
  __shared__ float yq[96], yk[96], yv[96];
  xs[t] = x[bl*128 + t];
  __syncthreads();
  float aq = 0.f, ak = 0.f, av = 0.f;
  for (int d = 0; d < 128; ++d) {
    float xv = xs[d];
    aq += xv * Wqs[d*128 + t];
    ak += xv * Wks[d*128 + t];
    av += xv * Wvs[d*128 + t];
  }
  int b = bl / LL, l = bl - (bl / LL) * LL;
  int n = t >> 4, dhs = t & 15;
  int rowbase = (b*NH + n)*LL + l;
  qs[rowbase*16 + dhs] = aq;
  ks[rowbase*16 + dhs] = ak;
  vs[rowbase*16 + dhs] = av;
  if (t < 96) {
    float pq = 0.f, pk = 0.f, pv = 0.f;
    for (int d = 0; d < 128; ++d) {
      float xv = xs[d];
      pq += xv * Wqp[d*96 + t];
      pk += xv * Wkp[d*96 + t];
      pv += xv * Wvp[d*96 + t];
    }
    yq[t] = pq; yk[t] = pk; yv[t] = pv;
  }
  __syncthreads();
  if (t < 96) {
    int np = t / 12;
    int rem = t - np*12;
    int p = rem / 3, c = rem - p*3;
    float rr0 = r[(bl*3 + 0)*3 + c];
    float rr1 = r[(bl*3 + 1)*3 + c];
    float rr2 = r[(bl*3 + 2)*3 + c];
    float tt  = tvec[bl*3 + c];
    int base = np*12 + p*3;
    int prow = (b*NH + np)*LL + l;
    qp[prow*12 + p*3 + c] = yq[base]*rr0 + yq[base+1]*rr1 + yq[base+2]*rr2 + tt;
    kp[prow*12 + p*3 + c] = yk[base]*rr0 + yk[base+1]*rr1 + yk[base+2]*rr2 + tt;
    vp[prow*12 + p*3 + c] = yv[base]*rr0 + yv[base+1]*rr1 + yv[base+2]*rr2 + tt;
  }
}

// ---------------- K2: bias_pair = e @ Wb  (writes (B,N,L,L) fp32) ----------------
// one thread per (b,i,j); grid 1152, block 256.
// Wb is read with compile-time-constant offsets -> wave-uniform -> s_load_dwordx8,
// no LDS, no barrier. Kernel becomes a pure e-stream.
__global__ __launch_bounds__(256) void k_bias(fp32p e, fp32p Wb, float* bias)
{
  int tid = blockIdx.x*256 + threadIdx.x;          // enumerates (b,i,j)
  int b = tid / (LL*LL);
  int rem = tid - b*(LL*LL);
  int i = rem / LL, j = rem - (rem / LL)*LL;
  const float4* erow = reinterpret_cast<const float4*>(e) + (size_t)tid * 32;
  float acc[8] = {0,0,0,0,0,0,0,0};
  #pragma unroll
  for (int it = 0; it < 32; ++it) {
    float4 v4 = erow[it];
    float vv[4] = {v4.x, v4.y, v4.z, v4.w};
    #pragma unroll
    for (int k = 0; k < 4; ++k) {
      float v = vv[k];
      #pragma unroll
      for (int nn = 0; nn < 8; ++nn) acc[nn] += v * Wb[(it*4 + k)*8 + nn];
    }
  }
  #pragma unroll
  for (int nn = 0; nn < 8; ++nn)
    bias[(((size_t)(b*NH + nn)*LL + i)*LL) + j] = acc[nn];
}

// ---------------- K3: fused logits + softmax + attn@{vs,vp,e} ----------------
// one block per (b,i); 256 threads (4 waves). attn never touches global memory.
// LDS: e tile 32KB + logits 12KB -> 3 blocks/CU.
__global__ __launch_bounds__(256) void k_fused(
    const float* __restrict__ qs, const float* __restrict__ ks,
    const float* __restrict__ vs, const float* __restrict__ qp,
    const float* __restrict__ kp, const float* __restrict__ vp,
    const float* __restrict__ bias, fp32p gamma, fp32p e,
    float* __restrict__ cat, float* __restrict__ opb)
{
  __shared__ float eS[64*128];       // one 64-row tile of e[b,i,:,:]
  __shared__ float lgS[NH*LL];       // logits, then unnormalized probs
  __shared__ float sS[NH];

  int bi = blockIdx.x;
  int b = bi / LL, i = bi - (bi / LL)*LL;
  int t = threadIdx.x;
  int n = t >> 5, l32 = t & 31;

  // prefetch tile 0 of e into registers (overlaps the whole logit phase)
  const float4* e4 = reinterpret_cast<const float4*>(e) + (size_t)bi * (LL*DD/4);
  float4 stg[8];
  #pragma unroll
  for (int rd = 0; rd < 8; ++rd) stg[rd] = e4[rd*256 + t];

  // ---- logits: thread covers (n, j = l32 + 32*jj) ----
  int rowq = (b*NH + n)*LL + i;
  int rowbase = (b*NH + n)*LL;
  float q[16], qpv[12];
  {
    const float4* q4 = reinterpret_cast<const float4*>(qs + (size_t)rowq*16);
    #pragma unroll
    for (int k2 = 0; k2 < 4; ++k2) { float4 v = q4[k2]; q[4*k2]=v.x; q[4*k2+1]=v.y; q[4*k2+2]=v.z; q[4*k2+3]=v.w; }
    const float4* p4 = reinterpret_cast<const float4*>(qp + (size_t)rowq*12);
    #pragma unroll
    for (int k2 = 0; k2 < 3; ++k2) { float4 v = p4[k2]; qpv[4*k2]=v.x; qpv[4*k2+1]=v.y; qpv[4*k2+2]=v.z; qpv[4*k2+3]=v.w; }
  }
  float qq = 0.f;
  #pragma unroll
  for (int k2 = 0; k2 < 12; ++k2) qq += qpv[k2]*qpv[k2];
  float coef = -0.125f * gamma[n];
  const float* brow = bias + (size_t)rowq*LL;
  for (int jj = 0; jj < 12; ++jj) {
    int j = l32 + jj*32;
    const float4* k4 = reinterpret_cast<const float4*>(ks + (size_t)(rowbase + j)*16);
    float dots = 0.f;
    #pragma unroll
    for (int k2 = 0; k2 < 4; ++k2) {
      float4 v = k4[k2];
      dots += q[4*k2]*v.x + q[4*k2+1]*v.y + q[4*k2+2]*v.z + q[4*k2+3]*v.w;
    }
    const float4* kp4 = reinterpret_cast<const float4*>(kp + (size_t)(rowbase + j)*12);
    float cross = 0.f, kk = 0.f;
    #pragma unroll
    for (int k2 = 0; k2 < 3; ++k2) {
      float4 v = kp4[k2];
      cross += qpv[4*k2]*v.x + qpv[4*k2+1]*v.y + qpv[4*k2+2]*v.z + qpv[4*k2+3]*v.w;
      kk += v.x*v.x + v.y*v.y + v.z*v.z + v.w*v.w;
    }
    lgS[n*LL + j] = 0.57735027f * (0.25f*dots + brow[j] + coef*(qq + kk - 2.f*cross));
  }
  __syncthreads();

  // ---- exact softmax in LDS: wave wv handles heads wv and wv+4 ----
  int wv = t >> 6, ln = t & 63;
  for (int nn = wv; nn < 8; nn += 4) {
    float v[6]; float m = -1e30f;
    #pragma unroll
    for (int k2 = 0; k2 < 6; ++k2) { v[k2] = lgS[nn*LL + ln + 64*k2]; m = fmaxf(m, v[k2]); }
    #pragma unroll
    for (int off = 32; off >= 1; off >>= 1) m = fmaxf(m, __shfl_xor(m, off, 64));
    float s = 0.f;
    #pragma unroll
    for (int k2 = 0; k2 < 6; ++k2) { float p = __expf(v[k2] - m); s += p; lgS[nn*LL + ln + 64*k2] = p; }
    #pragma unroll
    for (int off = 32; off >= 1; off >>= 1) s += __shfl_xor(s, off, 64);
    if (ln == 0) sS[nn] = s;
  }

  // ---- accumulate out_scalar / op / out_pair over 6 e-tiles ----
  float4 pacc = {0.f, 0.f, 0.f, 0.f};
  float sacc = 0.f;
  const float* pn = lgS + n*LL;
  const float* vrow0; int vstr;
  if (l32 < 16) { vrow0 = vs + (size_t)rowbase*16 + l32; vstr = 16; }
  else { int comp = (l32 < 28) ? (l32 - 16) : 0; vrow0 = vp + (size_t)rowbase*12 + comp; vstr = 12; }

  for (int tile = 0; tile < 6; ++tile) {
    __syncthreads();                       // prev tile consumed (iter0: softmax done)
    float4* eW = reinterpret_cast<float4*>(eS);
    #pragma unroll
    for (int rd = 0; rd < 8; ++rd) eW[rd*256 + t] = stg[rd];
    __syncthreads();
    if (tile < 5) {
      #pragma unroll
      for (int rd = 0; rd < 8; ++rd) stg[rd] = e4[(tile+1)*2048 + rd*256 + t];
    }
    const float* pt0 = pn + tile*64;
    const float* vrow = vrow0 + (size_t)tile*64*vstr;
    #pragma unroll 4
    for (int jj = 0; jj < 64; ++jj) {
      float a = pt0[jj];
      float4 ev = *reinterpret_cast<const float4*>(eS + jj*128 + l32*4);
      pacc.x += a*ev.x; pacc.y += a*ev.y; pacc.z += a*ev.z; pacc.w += a*ev.w;
      float vvl = vrow[(size_t)jj*vstr];
      sacc += a * vvl;
    }
  }

  float inv = 1.f / sS[n];
  float* cbase = cat + (size_t)bi*1280;
  if (l32 < 16)       cbase[n*16 + l32] = sacc * inv;
  else if (l32 < 28)  opb[(size_t)rowq*12 + (l32 - 16)] = sacc * inv;
  float4 pw;
  pw.x = pacc.x*inv; pw.y = pacc.y*inv; pw.z = pacc.z*inv; pw.w = pacc.w*inv;
  *reinterpret_cast<float4*>(cbase + 128 + n*128 + l32*4) = pw;
}

// ---------------- K5: inverse point transform + norms ----------------
// thread per (row, p); grid 96, block 256
__global__ __launch_bounds__(256) void k_pt(const float* opb, fp32p r, fp32p tvec, float* cat)
{
  int tid = blockIdx.x*256 + threadIdx.x;    // 24576
  int p = tid & 3;
  int row = tid >> 2;
  int i = row % LL;
  int bn = row / LL;
  int b = bn >> 3, n = bn & 7;
  int bi = b*LL + i;
  float o[3];
  #pragma unroll
  for (int k = 0; k < 3; ++k)
    o[k] = opb[(size_t)row*12 + p*3 + k] - tvec[bi*3 + k];
  float loc[3];
  #pragma unroll
  for (int c = 0; c < 3; ++c) {
    float s = 0.f;
    #pragma unroll
    for (int k = 0; k < 3; ++k) s += o[k] * r[(bi*3 + c)*3 + k];   // r[b,i,c,k]
    loc[c] = s;
  }
  float* dst = cat + (size_t)bi*1280;
  dst[1152 + n*12 + p*3 + 0] = loc[0];
  dst[1152 + n*12 + p*3 + 1] = loc[1];
  dst[1152 + n*12 + p*3 + 2] = loc[2];
  dst[1248 + n*4 + p] = sqrtf(loc[0]*loc[0] + loc[1]*loc[1] + loc[2]*loc[2]);
}

// ---------------- K6: out = cat @ Wo + bo ----------------
// 2 rows per block, k split across two halves of the block; grid 384, block 256
__global__ __launch_bounds__(256) void k_out(const float* cat, fp32p Wo, fp32p bo,
                                             float* out)
{
  __shared__ float catS[2*1280];
  __shared__ float red[2*128];
  int row0 = blockIdx.x*2;
  for (int idx = threadIdx.x; idx < 2*1280; idx += 256)
    catS[idx] = cat[(size_t)row0*1280 + idx];
  __syncthreads();
  int col = threadIdx.x & 127, half = threadIdx.x >> 7;
  float a0 = 0.f, a1 = 0.f;
  int k0 = half*640;
  for (int k = k0; k < k0 + 640; ++k) {
    float w = Wo[k*128 + col];
    a0 += catS[k]        * w;
    a1 += catS[1280 + k] * w;
  }
  if (half) { red[col] = a0; red[128 + col] = a1; }
  __syncthreads();
  if (!half) {
    float bv = bo[col];
    out[(size_t)(row0 + 0)*128 + col] = a0 + red[col]       + bv;
    out[(size_t)(row0 + 1)*128 + col] = a1 + red[128 + col] + bv;
  }
}

extern "C" void kernel_launch(void* const* d_in, const int* in_sizes, int n_in,
                              void* d_out, int out_size, void* d_ws, size_t ws_size,
                              hipStream_t stream)
{
  fp32p x    = (fp32p)d_in[0];
  fp32p e    = (fp32p)d_in[1];
  fp32p r    = (fp32p)d_in[2];
  fp32p tv   = (fp32p)d_in[3];
  fp32p Wqs  = (fp32p)d_in[4];
  fp32p Wks  = (fp32p)d_in[5];
  fp32p Wvs  = (fp32p)d_in[6];
  fp32p Wb   = (fp32p)d_in[7];
  fp32p Wqp  = (fp32p)d_in[8];
  fp32p Wkp  = (fp32p)d_in[9];
  fp32p Wvp  = (fp32p)d_in[10];
  fp32p gam  = (fp32p)d_in[11];
  fp32p Wo   = (fp32p)d_in[12];
  fp32p bo   = (fp32p)d_in[13];
  float* out = (float*)d_out;

  // ws partition (floats); total ~15.7 MB
  float* qs   = (float*)d_ws;
  float* ks   = qs + 98304;            // 6144*16
  float* vs   = ks + 98304;
  float* qp   = vs + 98304;            // 6144*12
  float* kp   = qp + 73728;
  float* vp   = kp + 73728;
  float* bias = vp + 73728;            // 2*8*384*384 (read by k_fused; attn never stored)
  float* opb  = bias + 2359296;        // 6144*12
  float* cat  = opb + 73728;           // 768*1280

  k_proj<<<768, 128, 0, stream>>>(x, r, tv, Wqs, Wks, Wvs, Wqp, Wkp, Wvp,
                                  qs, ks, vs, qp, kp, vp);
  k_bias<<<1152, 256, 0, stream>>>(e, Wb, bias);
  k_fused<<<768, 256, 0, stream>>>(qs, ks, vs, qp, kp, vp, bias, gam, e, cat, opb);
  k_pt<<<96, 256, 0, stream>>>(opb, r, tv, cat);
  k_out<<<384, 256, 0, stream>>>(cat, Wo, bo, out);
}

// Round 2
// 370.470 us; speedup vs baseline: 1.1411x; 1.0819x over previous
//
#include <hip/hip_runtime.h>

#define BB 2
#define LL 384
#define DD 128
#define NH 8

typedef const float* fp32p;

#define AS_G(p) (const __attribute__((address_space(1))) void*)(p)
#define AS_L(p) (__attribute__((address_space(3))) void*)(p)

// ---------------- K1: projections + point rotation ----------------
// grid 768 (b*L+l), block 128
__global__ __launch_bounds__(128) void k_proj(
    fp32p x, fp32p r, fp32p tvec,
    fp32p Wqs, fp32p Wks, fp32p Wvs,
    fp32p Wqp, fp32p Wkp, fp32p Wvp,
    float* qs, float* ks, float* vs,
    float* qp, float* kp, float* vp)
{
  int bl = blockIdx.x;
  int t = threadIdx.x;
  __shared__ float xs[128];
  __shared__ float yq[96], yk[96], yv[96];
  xs[t] = x[bl*128 + t];
  __syncthreads();
  float aq = 0.f, ak = 0.f, av = 0.f;
  for (int d = 0; d < 128; ++d) {
    float xv = xs[d];
    aq += xv * Wqs[d*128 + t];
    ak += xv * Wks[d*128 + t];
    av += xv * Wvs[d*128 + t];
  }
  int b = bl / LL, l = bl - (bl / LL) * LL;
  int n = t >> 4, dhs = t & 15;
  int rowbase = (b*NH + n)*LL + l;
  qs[rowbase*16 + dhs] = aq;
  ks[rowbase*16 + dhs] = ak;
  vs[rowbase*16 + dhs] = av;
  if (t < 96) {
    float pq = 0.f, pk = 0.f, pv = 0.f;
    for (int d = 0; d < 128; ++d) {
      float xv = xs[d];
      pq += xv * Wqp[d*96 + t];
      pk += xv * Wkp[d*96 + t];
      pv += xv * Wvp[d*96 + t];
    }
    yq[t] = pq; yk[t] = pk; yv[t] = pv;
  }
  __syncthreads();
  if (t < 96) {
    int np = t / 12;
    int rem = t - np*12;
    int p = rem / 3, c = rem - p*3;
    float rr0 = r[(bl*3 + 0)*3 + c];
    float rr1 = r[(bl*3 + 1)*3 + c];
    float rr2 = r[(bl*3 + 2)*3 + c];
    float tt  = tvec[bl*3 + c];
    int base = np*12 + p*3;
    int prow = (b*NH + np)*LL + l;
    qp[prow*12 + p*3 + c] = yq[base]*rr0 + yq[base+1]*rr1 + yq[base+2]*rr2 + tt;
    kp[prow*12 + p*3 + c] = yk[base]*rr0 + yk[base+1]*rr1 + yk[base+2]*rr2 + tt;
    vp[prow*12 + p*3 + c] = yv[base]*rr0 + yv[base+1]*rr1 + yv[base+2]*rr2 + tt;
  }
}

// ---------------- K2: bias_pair = e @ Wb  (writes (B,N,L,L) fp32) ----------------
// one thread per (b,i,j); grid 1152, block 256.
// Wb indices are compile-time constants -> wave-uniform -> scalar loads.
__global__ __launch_bounds__(256) void k_bias(fp32p e, fp32p Wb, float* bias)
{
  int tid = blockIdx.x*256 + threadIdx.x;          // enumerates (b,i,j)
  int b = tid / (LL*LL);
  int rem = tid - b*(LL*LL);
  int i = rem / LL, j = rem - (rem / LL)*LL;
  const float4* erow = reinterpret_cast<const float4*>(e) + (size_t)tid * 32;
  float acc[8] = {0,0,0,0,0,0,0,0};
  #pragma unroll
  for (int it = 0; it < 32; ++it) {
    float4 v4 = erow[it];
    float vv[4] = {v4.x, v4.y, v4.z, v4.w};
    #pragma unroll
    for (int k = 0; k < 4; ++k) {
      float v = vv[k];
      #pragma unroll
      for (int nn = 0; nn < 8; ++nn) acc[nn] += v * Wb[(it*4 + k)*8 + nn];
    }
  }
  #pragma unroll
  for (int nn = 0; nn < 8; ++nn)
    bias[(((size_t)(b*NH + nn)*LL + i)*LL) + j] = acc[nn];
}

// ---------------- K3: fused logits + softmax + attn@{vs,vp,e} ----------------
// one block per (b,i); 256 threads (4 waves). attn never touches global memory.
// e staged via global_load_lds into double-buffered 32-row tiles (no VGPR staging,
// no scratch spill). LDS: 2x16KB e + 12KB logits = 44.3KB -> 3 blocks/CU,
// 768 blocks all co-resident.
__global__ __launch_bounds__(256) void k_fused(
    const float* __restrict__ qs, const float* __restrict__ ks,
    const float* __restrict__ vs, const float* __restrict__ qp,
    const float* __restrict__ kp, const float* __restrict__ vp,
    const float* __restrict__ bias, fp32p gamma, fp32p e,
    float* __restrict__ cat, float* __restrict__ opb)
{
  __shared__ float eS[2][32*128];    // double-buffered e tile (16KB each)
  __shared__ float lgS[NH*LL];       // logits, then unnormalized probs
  __shared__ float sS[NH];

  int bi = blockIdx.x;
  int b = bi / LL, i = bi - (bi / LL)*LL;
  int t = threadIdx.x;
  int n = t >> 5, l32 = t & 31;
  int wbase = t & 192;               // wave-uniform part of t (w*64)

  const float4* e4 = reinterpret_cast<const float4*>(e) + (size_t)bi * (LL*DD/4);

  // issue tile-0 loads (global -> LDS direct); they complete under the logit phase
  {
    float4* dst = reinterpret_cast<float4*>(eS[0]);
    #pragma unroll
    for (int rd = 0; rd < 4; ++rd)
      __builtin_amdgcn_global_load_lds(AS_G(e4 + rd*256 + t),
                                       AS_L(dst + rd*256 + wbase), 16, 0, 0);
  }

  // ---- logits: thread covers (n, j = l32 + 32*jj) ----
  int rowq = (b*NH + n)*LL + i;
  int rowbase = (b*NH + n)*LL;
  float q[16], qpv[12];
  {
    const float4* q4 = reinterpret_cast<const float4*>(qs + (size_t)rowq*16);
    #pragma unroll
    for (int k2 = 0; k2 < 4; ++k2) { float4 v = q4[k2]; q[4*k2]=v.x; q[4*k2+1]=v.y; q[4*k2+2]=v.z; q[4*k2+3]=v.w; }
    const float4* p4 = reinterpret_cast<const float4*>(qp + (size_t)rowq*12);
    #pragma unroll
    for (int k2 = 0; k2 < 3; ++k2) { float4 v = p4[k2]; qpv[4*k2]=v.x; qpv[4*k2+1]=v.y; qpv[4*k2+2]=v.z; qpv[4*k2+3]=v.w; }
  }
  float qq = 0.f;
  #pragma unroll
  for (int k2 = 0; k2 < 12; ++k2) qq += qpv[k2]*qpv[k2];
  float coef = -0.125f * gamma[n];
  const float* brow = bias + (size_t)rowq*LL;
  for (int jj = 0; jj < 12; ++jj) {
    int j = l32 + jj*32;
    const float4* k4 = reinterpret_cast<const float4*>(ks + (size_t)(rowbase + j)*16);
    float dots = 0.f;
    #pragma unroll
    for (int k2 = 0; k2 < 4; ++k2) {
      float4 v = k4[k2];
      dots += q[4*k2]*v.x + q[4*k2+1]*v.y + q[4*k2+2]*v.z + q[4*k2+3]*v.w;
    }
    const float4* kp4 = reinterpret_cast<const float4*>(kp + (size_t)(rowbase + j)*12);
    float cross = 0.f, kk = 0.f;
    #pragma unroll
    for (int k2 = 0; k2 < 3; ++k2) {
      float4 v = kp4[k2];
      cross += qpv[4*k2]*v.x + qpv[4*k2+1]*v.y + qpv[4*k2+2]*v.z + qpv[4*k2+3]*v.w;
      kk += v.x*v.x + v.y*v.y + v.z*v.z + v.w*v.w;
    }
    lgS[n*LL + j] = 0.57735027f * (0.25f*dots + brow[j] + coef*(qq + kk - 2.f*cross));
  }
  __syncthreads();   // logits visible; vmcnt(0) drain also guarantees tile 0 resident

  // ---- exact softmax in LDS: wave wv handles heads wv and wv+4 ----
  int wv = t >> 6, ln = t & 63;
  for (int nn = wv; nn < 8; nn += 4) {
    float v[6]; float m = -1e30f;
    #pragma unroll
    for (int k2 = 0; k2 < 6; ++k2) { v[k2] = lgS[nn*LL + ln + 64*k2]; m = fmaxf(m, v[k2]); }
    #pragma unroll
    for (int off = 32; off >= 1; off >>= 1) m = fmaxf(m, __shfl_xor(m, off, 64));
    float s = 0.f;
    #pragma unroll
    for (int k2 = 0; k2 < 6; ++k2) { float p = __expf(v[k2] - m); s += p; lgS[nn*LL + ln + 64*k2] = p; }
    #pragma unroll
    for (int off = 32; off >= 1; off >>= 1) s += __shfl_xor(s, off, 64);
    if (ln == 0) sS[nn] = s;
  }
  __syncthreads();   // probs + sums visible

  // ---- accumulate out_scalar / op / out_pair over 12 e-tiles of 32 rows ----
  float4 pacc = {0.f, 0.f, 0.f, 0.f};
  float sacc = 0.f;
  const float* pn = lgS + n*LL;
  const float* vrow0; int vstr;
  if (l32 < 16) { vrow0 = vs + (size_t)rowbase*16 + l32; vstr = 16; }
  else { int comp = (l32 < 28) ? (l32 - 16) : 0; vrow0 = vp + (size_t)rowbase*12 + comp; vstr = 12; }

  for (int tile = 0; tile < 12; ++tile) {
    if (tile < 11) {                 // issue next tile into the other buffer
      const float4* src = e4 + (tile+1)*1024;
      float4* dst = reinterpret_cast<float4*>(eS[(tile+1)&1]);
      #pragma unroll
      for (int rd = 0; rd < 4; ++rd)
        __builtin_amdgcn_global_load_lds(AS_G(src + rd*256 + t),
                                         AS_L(dst + rd*256 + wbase), 16, 0, 0);
    }
    const float* eT = eS[tile&1];
    const float* pt0 = pn + tile*32;
    const float* vrow = vrow0 + (size_t)tile*32*vstr;
    #pragma unroll 4
    for (int jj = 0; jj < 32; ++jj) {
      float a = pt0[jj];
      float4 ev = *reinterpret_cast<const float4*>(eT + jj*128 + l32*4);
      pacc.x += a*ev.x; pacc.y += a*ev.y; pacc.z += a*ev.z; pacc.w += a*ev.w;
      sacc += a * vrow[(size_t)jj*vstr];
    }
    __syncthreads();                 // drains next-tile loads; frees buf for reuse
  }

  float inv = 1.f / sS[n];
  float* cbase = cat + (size_t)bi*1280;
  if (l32 < 16)       cbase[n*16 + l32] = sacc * inv;
  else if (l32 < 28)  opb[(size_t)rowq*12 + (l32 - 16)] = sacc * inv;
  float4 pw;
  pw.x = pacc.x*inv; pw.y = pacc.y*inv; pw.z = pacc.z*inv; pw.w = pacc.w*inv;
  *reinterpret_cast<float4*>(cbase + 128 + n*128 + l32*4) = pw;
}

// ---------------- K5: inverse point transform + norms ----------------
// thread per (row, p); grid 96, block 256
__global__ __launch_bounds__(256) void k_pt(const float* opb, fp32p r, fp32p tvec, float* cat)
{
  int tid = blockIdx.x*256 + threadIdx.x;    // 24576
  int p = tid & 3;
  int row = tid >> 2;
  int i = row % LL;
  int bn = row / LL;
  int b = bn >> 3, n = bn & 7;
  int bi = b*LL + i;
  float o[3];
  #pragma unroll
  for (int k = 0; k < 3; ++k)
    o[k] = opb[(size_t)row*12 + p*3 + k] - tvec[bi*3 + k];
  float loc[3];
  #pragma unroll
  for (int c = 0; c < 3; ++c) {
    float s = 0.f;
    #pragma unroll
    for (int k = 0; k < 3; ++k) s += o[k] * r[(bi*3 + c)*3 + k];   // r[b,i,c,k]
    loc[c] = s;
  }
  float* dst = cat + (size_t)bi*1280;
  dst[1152 + n*12 + p*3 + 0] = loc[0];
  dst[1152 + n*12 + p*3 + 1] = loc[1];
  dst[1152 + n*12 + p*3 + 2] = loc[2];
  dst[1248 + n*4 + p] = sqrtf(loc[0]*loc[0] + loc[1]*loc[1] + loc[2]*loc[2]);
}

// ---------------- K6: out = cat @ Wo + bo ----------------
// 2 rows per block, k split across two halves of the block; grid 384, block 256
__global__ __launch_bounds__(256) void k_out(const float* cat, fp32p Wo, fp32p bo,
                                             float* out)
{
  __shared__ float catS[2*1280];
  __shared__ float red[2*128];
  int row0 = blockIdx.x*2;
  for (int idx = threadIdx.x; idx < 2*1280; idx += 256)
    catS[idx] = cat[(size_t)row0*1280 + idx];
  __syncthreads();
  int col = threadIdx.x & 127, half = threadIdx.x >> 7;
  float a0 = 0.f, a1 = 0.f;
  int k0 = half*640;
  for (int k = k0; k < k0 + 640; ++k) {
    float w = Wo[k*128 + col];
    a0 += catS[k]        * w;
    a1 += catS[1280 + k] * w;
  }
  if (half) { red[col] = a0; red[128 + col] = a1; }
  __syncthreads();
  if (!half) {
    float bv = bo[col];
    out[(size_t)(row0 + 0)*128 + col] = a0 + red[col]       + bv;
    out[(size_t)(row0 + 1)*128 + col] = a1 + red[128 + col] + bv;
  }
}

extern "C" void kernel_launch(void* const* d_in, const int* in_sizes, int n_in,
                              void* d_out, int out_size, void* d_ws, size_t ws_size,
                              hipStream_t stream)
{
  fp32p x    = (fp32p)d_in[0];
  fp32p e    = (fp32p)d_in[1];
  fp32p r    = (fp32p)d_in[2];
  fp32p tv   = (fp32p)d_in[3];
  fp32p Wqs  = (fp32p)d_in[4];
  fp32p Wks  = (fp32p)d_in[5];
  fp32p Wvs  = (fp32p)d_in[6];
  fp32p Wb   = (fp32p)d_in[7];
  fp32p Wqp  = (fp32p)d_in[8];
  fp32p Wkp  = (fp32p)d_in[9];
  fp32p Wvp  = (fp32p)d_in[10];
  fp32p gam  = (fp32p)d_in[11];
  fp32p Wo   = (fp32p)d_in[12];
  fp32p bo   = (fp32p)d_in[13];
  float* out = (float*)d_out;

  // ws partition (floats); total ~15.7 MB
  float* qs   = (float*)d_ws;
  float* ks   = qs + 98304;            // 6144*16
  float* vs   = ks + 98304;
  float* qp   = vs + 98304;            // 6144*12
  float* kp   = qp + 73728;
  float* vp   = kp + 73728;
  float* bias = vp + 73728;            // 2*8*384*384 (read by k_fused; attn never stored)
  float* opb  = bias + 2359296;        // 6144*12
  float* cat  = opb + 73728;           // 768*1280

  k_proj<<<768, 128, 0, stream>>>(x, r, tv, Wqs, Wks, Wvs, Wqp, Wkp, Wvp,
                                  qs, ks, vs, qp, kp, vp);
  k_bias<<<1152, 256, 0, stream>>>(e, Wb, bias);
  k_fused<<<768, 256, 0, stream>>>(qs, ks, vs, qp, kp, vp, bias, gam, e, cat, opb);
  k_pt<<<96, 256, 0, stream>>>(opb, r, tv, cat);
  k_out<<<384, 256, 0, stream>>>(cat, Wo, bo, out);
}